// Round 1
// baseline (26766.663 us; speedup 1.0000x reference)
//
#include <hip/hip_runtime.h>

typedef _Float16 h16;
typedef __attribute__((ext_vector_type(2))) _Float16 h16x2;
typedef __attribute__((ext_vector_type(4))) _Float16 h16x4;
typedef __attribute__((ext_vector_type(8))) _Float16 h16x8;
typedef __attribute__((ext_vector_type(4))) float    f32x4;

constexpr int B_  = 16;
constexpr int T_  = 2048;
constexpr int D_  = 512;
constexpr int H_  = 512;
constexpr int O_  = 256;
constexpr int G4_ = 2048;           // 4*H
constexpr int BT_ = B_ * T_;

__device__ __forceinline__ float sigm(float x)   { return 1.f / (1.f + __expf(-x)); }
__device__ __forceinline__ float tanh_f(float x) { return 1.f - 2.f / (1.f + __expf(2.f * x)); }

// ---------------- prep: fp32 x -> fp16 X, and mask bits ----------------
__global__ void k_prep_x(const float* __restrict__ x, h16* __restrict__ Xh,
                         unsigned* __restrict__ maskbits) {
  const int row = blockIdx.x;              // b*T + t
  const int b = row >> 11, t = row & 2047;
  const float2* xr = (const float2*)(x + (size_t)row * D_);
  float2 v = xr[threadIdx.x];
  h16x2 hv = { (h16)v.x, (h16)v.y };
  *(h16x2*)(Xh + (size_t)row * D_ + threadIdx.x * 2) = hv;
  float s = v.x + v.y;
  #pragma unroll
  for (int off = 32; off > 0; off >>= 1) s += __shfl_down(s, off, 64);
  __shared__ float red[4];
  const int lane = threadIdx.x & 63, wv = threadIdx.x >> 6;
  if (lane == 0) red[wv] = s;
  __syncthreads();
  if (threadIdx.x == 0) {
    float tot = red[0] + red[1] + red[2] + red[3];
    if (tot != 0.f) atomicOr(&maskbits[t], 1u << b);
  }
}

// ---------------- fp32 -> fp16 convert (weights) ----------------
__global__ void k_cvt(const float* __restrict__ s, h16* __restrict__ d, int n4) {
  int i = blockIdx.x * 256 + threadIdx.x;
  if (i < n4) {
    f32x4 v = ((const f32x4*)s)[i];
    h16x4 o = { (h16)v.x, (h16)v.y, (h16)v.z, (h16)v.w };
    ((h16x4*)d)[i] = o;
  }
}

__global__ void k_bias(const float* __restrict__ a, const float* __restrict__ b,
                       float* __restrict__ o, int n) {
  int i = blockIdx.x * 256 + threadIdx.x;
  if (i < n) o[i] = a[i] + b[i];
}

// ---------------- GEMM: C[m][n] = sum_k A[m,k]*B[n,k]  (both K-contiguous) ----------------
// 128x128 tile, BK=32, 4 waves in 2x2, each wave 4x4 frags of 16x16x32 MFMA.
__global__ __launch_bounds__(256, 2)
void k_gemm(const h16* __restrict__ A, const h16* __restrict__ Bm, h16* __restrict__ C,
            int M, int N, int K) {
  __shared__ h16 As[128 * 32];
  __shared__ h16 Bs[128 * 32];
  const int tiles_n = N >> 7;
  const int tm = blockIdx.x / tiles_n, tn = blockIdx.x % tiles_n;
  const int tid = threadIdx.x, lane = tid & 63, wv = tid >> 6;
  const int wm = (wv >> 1) * 64, wn = (wv & 1) * 64;
  const int ml = lane & 15, qd = lane >> 4;
  f32x4 acc[4][4] = {};
  const h16* Arow = A + (size_t)(tm * 128) * K;
  const h16* Brow = Bm + (size_t)(tn * 128) * K;
  for (int kt = 0; kt < K; kt += 32) {
    __syncthreads();
    #pragma unroll
    for (int p = 0; p < 2; ++p) {
      int ch = tid + p * 256;
      int r = ch >> 2, qq = ch & 3;
      int sidx = r * 4 + ((qq + r) & 3);     // XOR swizzle to spread banks
      *(h16x8*)(As + sidx * 8) = *(const h16x8*)(Arow + (size_t)r * K + kt + qq * 8);
      *(h16x8*)(Bs + sidx * 8) = *(const h16x8*)(Brow + (size_t)r * K + kt + qq * 8);
    }
    __syncthreads();
    h16x8 af[4], bfv[4];
    #pragma unroll
    for (int i = 0; i < 4; ++i) {
      int ra = wm + i * 16 + ml;
      af[i]  = *(const h16x8*)(As + (ra * 4 + ((qd + ra) & 3)) * 8);
      int rb = wn + i * 16 + ml;
      bfv[i] = *(const h16x8*)(Bs + (rb * 4 + ((qd + rb) & 3)) * 8);
    }
    #pragma unroll
    for (int i = 0; i < 4; ++i)
      #pragma unroll
      for (int j = 0; j < 4; ++j)
        acc[i][j] = __builtin_amdgcn_mfma_f32_16x16x32_f16(af[i], bfv[j], acc[i][j], 0, 0, 0);
  }
  const int colb = lane & 15, rowq = (lane >> 4) * 4;
  #pragma unroll
  for (int i = 0; i < 4; ++i)
    #pragma unroll
    for (int j = 0; j < 4; ++j) {
      int row0 = tm * 128 + wm + i * 16 + rowq;
      int col  = tn * 128 + wn + j * 16 + colb;
      #pragma unroll
      for (int r = 0; r < 4; ++r)
        C[(size_t)(row0 + r) * N + col] = (h16)acc[i][j][r];
    }
}

// ---------------- persistent recurrence ----------------
// 32 WGs; WG g owns h-slice j in [16g,16g+16) for ALL 16 samples.
// wave w (0..3) = gate type (i,f,g,o): rows w*512 + 16g + m. Whh frags resident in VGPRs.
// h exchange: Hbuf[parity][sample][k] u32 = (tag<<16)|fp16bits, agent-scope atomics.
__global__ __launch_bounds__(256, 1)
void k_lstm(const h16* __restrict__ G, const h16* __restrict__ Whh,
            const float* __restrict__ bias, const unsigned* __restrict__ maskbits,
            unsigned* Hbuf, h16* seq_out, float* hT_out, int store_seq) {
  const int g = blockIdx.x;
  const int tid = threadIdx.x, lane = tid & 63, w = tid >> 6;
  const int nl = lane & 15, qd = lane >> 4;
  __shared__ h16 Hst[16 * 520];           // [sample][k], padded to break banks
  __shared__ float gate_ex[4][16][16];    // [gate][jj][sample]
  __shared__ float c_st[16][16];          // [jj][sample]
  __shared__ unsigned mword;

  // resident A-fragments: rows w*512 + g*16 + (lane&15), k = kt*32 + qd*8 + j
  h16x8 afr[16];
  {
    const h16* wr = Whh + (size_t)(w * 512 + g * 16 + nl) * 512 + qd * 8;
    #pragma unroll
    for (int kt = 0; kt < 16; ++kt) afr[kt] = *(const h16x8*)(wr + kt * 32);
  }
  float bias_v[4];
  #pragma unroll
  for (int r = 0; r < 4; ++r) bias_v[r] = bias[w * 512 + g * 16 + qd * 4 + r];

  c_st[tid >> 4][tid & 15] = 0.f;
  for (int i = tid; i < 16 * 520; i += 256) Hst[i] = (h16)0.f;
  __syncthreads();

  for (int t = 0; t < T_; ++t) {
    if (t > 0) {
      const int par = t & 1;
      const unsigned tag = (unsigned)t << 16;
      const unsigned* src = Hbuf + (size_t)(par * 16 + (tid >> 4)) * 512 + (tid & 15) * 32;
      unsigned v[32];
      for (;;) {
        bool ok = true;
        #pragma unroll
        for (int i = 0; i < 32; ++i)
          v[i] = __hip_atomic_load(src + i, __ATOMIC_RELAXED, __HIP_MEMORY_SCOPE_AGENT);
        #pragma unroll
        for (int i = 0; i < 32; ++i) ok &= ((v[i] & 0xffff0000u) == tag);
        if (ok) break;
      }
      h16* dst = Hst + (tid >> 4) * 520 + (tid & 15) * 32;
      #pragma unroll
      for (int i = 0; i < 32; ++i) {
        unsigned short hb = (unsigned short)(v[i] & 0xffffu);
        h16 hv; __builtin_memcpy(&hv, &hb, 2);
        dst[i] = hv;
      }
    }
    if (tid == 0) mword = maskbits[t];
    __syncthreads();

    f32x4 acc = {0.f, 0.f, 0.f, 0.f};
    #pragma unroll
    for (int kt = 0; kt < 16; ++kt) {
      h16x8 bfr = *(const h16x8*)(Hst + nl * 520 + kt * 32 + qd * 8);
      acc = __builtin_amdgcn_mfma_f32_16x16x32_f16(afr[kt], bfr, acc, 0, 0, 0);
    }
    // add precomputed x-gates + bias, activate (wave-uniform branch)
    const h16* gp = G + ((size_t)nl * T_ + t) * G4_ + w * 512 + g * 16 + qd * 4;
    h16x4 gv = *(const h16x4*)gp;
    #pragma unroll
    for (int r = 0; r < 4; ++r) {
      float pre = acc[r] + bias_v[r] + (float)gv[r];
      float a = (w == 2) ? tanh_f(pre) : sigm(pre);
      gate_ex[w][qd * 4 + r][nl] = a;
    }
    __syncthreads();
    {
      const int jj = tid >> 4, n = tid & 15;
      float iv = gate_ex[0][jj][n], fv = gate_ex[1][jj][n];
      float gg = gate_ex[2][jj][n], ov = gate_ex[3][jj][n];
      float c_old = c_st[jj][n];
      bool msk = (mword >> n) & 1u;
      float c_new = msk ? (fv * c_old + iv * gg) : c_old;
      float h_old = (float)Hst[n * 520 + g * 16 + jj];
      float h_new = msk ? (ov * tanh_f(c_new)) : h_old;
      c_st[jj][n] = c_new;
      h16 hh = (h16)h_new;
      unsigned short hb; __builtin_memcpy(&hb, &hh, 2);
      unsigned pv = ((unsigned)(t + 1) << 16) | (unsigned)hb;
      __hip_atomic_store(Hbuf + (size_t)((((t + 1) & 1) * 16) + n) * 512 + g * 16 + jj, pv,
                         __ATOMIC_RELAXED, __HIP_MEMORY_SCOPE_AGENT);
      if (store_seq) seq_out[((size_t)n * T_ + t) * H_ + g * 16 + jj] = hh;
      if (hT_out && t == T_ - 1) hT_out[n * H_ + g * 16 + jj] = h_new;
    }
    __syncthreads();
  }
}

// ---------------- final FC: out = hT @ Wfc^T + bfc (fp32) ----------------
__global__ void k_fc(const float* __restrict__ hT, const float* __restrict__ Wfc,
                     const float* __restrict__ bfc, float* __restrict__ out) {
  const int b = blockIdx.x;
  __shared__ float hs[H_];
  for (int i = threadIdx.x; i < H_; i += 256) hs[i] = hT[(size_t)b * H_ + i];
  __syncthreads();
  const int o = threadIdx.x;
  const float* wr = Wfc + (size_t)o * H_;
  float s = bfc[o];
  for (int k = 0; k < H_; k += 4) {
    f32x4 w4 = *(const f32x4*)(wr + k);
    s += hs[k] * w4.x + hs[k + 1] * w4.y + hs[k + 2] * w4.z + hs[k + 3] * w4.w;
  }
  out[(size_t)b * O_ + o] = s;
}

extern "C" void kernel_launch(void* const* d_in, const int* in_sizes, int n_in,
                              void* d_out, int out_size, void* d_ws, size_t ws_size,
                              hipStream_t stream) {
  const float* x    = (const float*)d_in[0];
  const float* Wih0 = (const float*)d_in[1];
  const float* Whh0 = (const float*)d_in[2];
  const float* bih0 = (const float*)d_in[3];
  const float* bhh0 = (const float*)d_in[4];
  const float* Wih1 = (const float*)d_in[5];
  const float* Whh1 = (const float*)d_in[6];
  const float* bih1 = (const float*)d_in[7];
  const float* bhh1 = (const float*)d_in[8];
  const float* Wfc  = (const float*)d_in[9];
  const float* bfc  = (const float*)d_in[10];

  char* base = (char*)d_ws;
  size_t off = 0;
  auto alloc = [&](size_t bytes) -> void* {
    void* r = base + off;
    off = (off + bytes + 255) & ~(size_t)255;
    return r;
  };
  h16* Xh   = (h16*)alloc((size_t)BT_ * D_ * 2);
  h16* Gbuf = (h16*)alloc((size_t)BT_ * G4_ * 2);
  h16* seq1 = (h16*)alloc((size_t)BT_ * H_ * 2);
  h16* Wb0  = (h16*)alloc((size_t)G4_ * D_ * 2);
  h16* Wb1  = (h16*)alloc((size_t)G4_ * H_ * 2);
  h16* Wb2  = (h16*)alloc((size_t)G4_ * H_ * 2);
  h16* Wb3  = (h16*)alloc((size_t)G4_ * H_ * 2);
  float* bs0 = (float*)alloc(G4_ * 4);
  float* bs1 = (float*)alloc(G4_ * 4);
  unsigned* maskbits = (unsigned*)alloc(T_ * 4);
  unsigned* Hbuf0 = (unsigned*)alloc((size_t)2 * 16 * 512 * 4);
  unsigned* Hbuf1 = (unsigned*)alloc((size_t)2 * 16 * 512 * 4);
  float* hT = (float*)alloc((size_t)B_ * H_ * 4);

  hipMemsetAsync(maskbits, 0, T_ * 4, stream);
  k_prep_x<<<BT_, 256, 0, stream>>>(x, Xh, maskbits);
  const int wn4 = G4_ * D_ / 4;
  k_cvt<<<(wn4 + 255) / 256, 256, 0, stream>>>(Wih0, Wb0, wn4);
  k_cvt<<<(wn4 + 255) / 256, 256, 0, stream>>>(Whh0, Wb1, wn4);
  k_cvt<<<(wn4 + 255) / 256, 256, 0, stream>>>(Wih1, Wb2, wn4);
  k_cvt<<<(wn4 + 255) / 256, 256, 0, stream>>>(Whh1, Wb3, wn4);
  k_bias<<<(G4_ + 255) / 256, 256, 0, stream>>>(bih0, bhh0, bs0, G4_);
  k_bias<<<(G4_ + 255) / 256, 256, 0, stream>>>(bih1, bhh1, bs1, G4_);

  k_gemm<<<(BT_ / 128) * (G4_ / 128), 256, 0, stream>>>(Xh, Wb0, Gbuf, BT_, G4_, D_);
  k_lstm<<<32, 256, 0, stream>>>(Gbuf, Wb1, bs0, maskbits, Hbuf0, seq1, nullptr, 1);
  k_gemm<<<(BT_ / 128) * (G4_ / 128), 256, 0, stream>>>(seq1, Wb2, Gbuf, BT_, G4_, H_);
  k_lstm<<<32, 256, 0, stream>>>(Gbuf, Wb3, bs1, maskbits, Hbuf1, nullptr, hT, 0);
  k_fc<<<B_, 256, 0, stream>>>(hT, Wfc, bfc, (float*)d_out);
}

// Round 2
// 16286.108 us; speedup vs baseline: 1.6435x; 1.6435x over previous
//
#include <hip/hip_runtime.h>

typedef _Float16 h16;
typedef __attribute__((ext_vector_type(2))) _Float16 h16x2;
typedef __attribute__((ext_vector_type(4))) _Float16 h16x4;
typedef __attribute__((ext_vector_type(8))) _Float16 h16x8;
typedef __attribute__((ext_vector_type(4))) float    f32x4;

constexpr int B_  = 16;
constexpr int T_  = 2048;
constexpr int D_  = 512;
constexpr int H_  = 512;
constexpr int O_  = 256;
constexpr int G4_ = 2048;           // 4*H
constexpr int BT_ = B_ * T_;

__device__ __forceinline__ float sigm(float x)   { return 1.f / (1.f + __expf(-x)); }
__device__ __forceinline__ float tanh_f(float x) { return 1.f - 2.f / (1.f + __expf(2.f * x)); }

// ---------------- prep: fp32 x -> fp16 X, and mask bits ----------------
__global__ void k_prep_x(const float* __restrict__ x, h16* __restrict__ Xh,
                         unsigned* __restrict__ maskbits) {
  const int row = blockIdx.x;              // b*T + t
  const int b = row >> 11, t = row & 2047;
  const float2* xr = (const float2*)(x + (size_t)row * D_);
  float2 v = xr[threadIdx.x];
  h16x2 hv = { (h16)v.x, (h16)v.y };
  *(h16x2*)(Xh + (size_t)row * D_ + threadIdx.x * 2) = hv;
  float s = v.x + v.y;
  #pragma unroll
  for (int off = 32; off > 0; off >>= 1) s += __shfl_down(s, off, 64);
  __shared__ float red[4];
  const int lane = threadIdx.x & 63, wv = threadIdx.x >> 6;
  if (lane == 0) red[wv] = s;
  __syncthreads();
  if (threadIdx.x == 0) {
    float tot = red[0] + red[1] + red[2] + red[3];
    if (tot != 0.f) atomicOr(&maskbits[t], 1u << b);
  }
}

// ---------------- fp32 -> fp16 convert (weights) ----------------
__global__ void k_cvt(const float* __restrict__ s, h16* __restrict__ d, int n4) {
  int i = blockIdx.x * 256 + threadIdx.x;
  if (i < n4) {
    f32x4 v = ((const f32x4*)s)[i];
    h16x4 o = { (h16)v.x, (h16)v.y, (h16)v.z, (h16)v.w };
    ((h16x4*)d)[i] = o;
  }
}

__global__ void k_bias(const float* __restrict__ a, const float* __restrict__ b,
                       float* __restrict__ o, int n) {
  int i = blockIdx.x * 256 + threadIdx.x;
  if (i < n) o[i] = a[i] + b[i];
}

// ---------------- GEMM: C[m][n] = sum_k A[m,k]*B[n,k]  (both K-contiguous) ----------------
__global__ __launch_bounds__(256, 2)
void k_gemm(const h16* __restrict__ A, const h16* __restrict__ Bm, h16* __restrict__ C,
            int M, int N, int K) {
  __shared__ h16 As[128 * 32];
  __shared__ h16 Bs[128 * 32];
  const int tiles_n = N >> 7;
  const int tm = blockIdx.x / tiles_n, tn = blockIdx.x % tiles_n;
  const int tid = threadIdx.x, lane = tid & 63, wv = tid >> 6;
  const int wm = (wv >> 1) * 64, wn = (wv & 1) * 64;
  const int ml = lane & 15, qd = lane >> 4;
  f32x4 acc[4][4] = {};
  const h16* Arow = A + (size_t)(tm * 128) * K;
  const h16* Brow = Bm + (size_t)(tn * 128) * K;
  for (int kt = 0; kt < K; kt += 32) {
    __syncthreads();
    #pragma unroll
    for (int p = 0; p < 2; ++p) {
      int ch = tid + p * 256;
      int r = ch >> 2, qq = ch & 3;
      int sidx = r * 4 + ((qq + r) & 3);     // XOR swizzle to spread banks
      *(h16x8*)(As + sidx * 8) = *(const h16x8*)(Arow + (size_t)r * K + kt + qq * 8);
      *(h16x8*)(Bs + sidx * 8) = *(const h16x8*)(Brow + (size_t)r * K + kt + qq * 8);
    }
    __syncthreads();
    h16x8 af[4], bfv[4];
    #pragma unroll
    for (int i = 0; i < 4; ++i) {
      int ra = wm + i * 16 + ml;
      af[i]  = *(const h16x8*)(As + (ra * 4 + ((qd + ra) & 3)) * 8);
      int rb = wn + i * 16 + ml;
      bfv[i] = *(const h16x8*)(Bs + (rb * 4 + ((qd + rb) & 3)) * 8);
    }
    #pragma unroll
    for (int i = 0; i < 4; ++i)
      #pragma unroll
      for (int j = 0; j < 4; ++j)
        acc[i][j] = __builtin_amdgcn_mfma_f32_16x16x32_f16(af[i], bfv[j], acc[i][j], 0, 0, 0);
  }
  const int colb = lane & 15, rowq = (lane >> 4) * 4;
  #pragma unroll
  for (int i = 0; i < 4; ++i)
    #pragma unroll
    for (int j = 0; j < 4; ++j) {
      int row0 = tm * 128 + wm + i * 16 + rowq;
      int col  = tn * 128 + wn + j * 16 + colb;
      #pragma unroll
      for (int r = 0; r < 4; ++r)
        C[(size_t)(row0 + r) * N + col] = (h16)acc[i][j][r];
    }
}

// ---------------- fused 2-layer persistent recurrence ----------------
// 64 WGs: wg<32 => layer0 slice g=wg ; wg>=32 => layer1 slice g=wg-32.
// Rings: depth-4, word = (tag<<16)|fp16, single writer per word, agent-scope.
// L0 publishes h0 tag t+1 -> H0ring slot (t+1)&3. L1 consumes h0 tag t+1,
// publishes h1 tag t+1 -> H1ring. L0 back-pressure: before publishing tag t+1
// (t>=4), block-collectively verify H1 holds tag >= t-3 in slot (t-3)&3
// (covers all 32 L1 WGs; barrier before publish makes it collective).
__device__ __forceinline__ void poll_ring(const unsigned* ring, int slot, unsigned tag,
                                          int sample, int chunk, h16* HstDst) {
  const unsigned long long* src = (const unsigned long long*)
      (ring + ((size_t)slot * 16 + sample) * 512 + chunk * 32);
  const unsigned long long expw =
      ((unsigned long long)tag << 16) | ((unsigned long long)tag << 48);
  unsigned long long v[16];
  for (;;) {
    bool ok = true;
    #pragma unroll
    for (int i = 0; i < 16; ++i)
      v[i] = __hip_atomic_load(src + i, __ATOMIC_RELAXED, __HIP_MEMORY_SCOPE_AGENT);
    #pragma unroll
    for (int i = 0; i < 16; ++i)
      ok &= ((v[i] & 0xFFFF0000FFFF0000ull) == expw);
    if (ok) break;
    __builtin_amdgcn_s_sleep(1);
  }
  unsigned* dst = (unsigned*)(HstDst + sample * 520 + chunk * 32);
  #pragma unroll
  for (int i = 0; i < 16; ++i)
    dst[i] = (unsigned)(v[i] & 0xffffull) | ((unsigned)((v[i] >> 32) & 0xffffull) << 16);
}

__global__ __launch_bounds__(256, 1)
void k_lstm2(const h16* __restrict__ G,
             const h16* __restrict__ Whh0,
             const h16* __restrict__ Wih1,
             const h16* __restrict__ Whh1,
             const float* __restrict__ bias0,
             const float* __restrict__ bias1,
             const unsigned* __restrict__ maskbits,
             unsigned* H0ring, unsigned* H1ring, float* hT_out) {
  const int wg = blockIdx.x;
  const bool l1 = wg >= 32;
  const int g = l1 ? (wg - 32) : wg;
  const int tid = threadIdx.x, lane = tid & 63, w = tid >> 6;
  const int nl = lane & 15, qd = lane >> 4;
  const int sample = tid >> 4, chunk = tid & 15;

  __shared__ h16 Hst0[16 * 520];          // B-tile: h0 (L0: prev h0; L1: current h0)
  __shared__ h16 Hst1[16 * 520];          // B-tile: h1 prev (L1 only)
  __shared__ float gate_ex[4][16][16];    // [gate][jj][sample]
  __shared__ float c_st[16][16];
  __shared__ unsigned mword;

  // resident weights: rows w*512 + g*16 + (lane&15), k = kt*32 + qd*8 + j
  h16x8 a_hh[16], a_ih[16];
  {
    const h16* Whh = l1 ? Whh1 : Whh0;
    const h16* wr = Whh + (size_t)(w * 512 + g * 16 + nl) * 512 + qd * 8;
    #pragma unroll
    for (int kt = 0; kt < 16; ++kt) a_hh[kt] = *(const h16x8*)(wr + kt * 32);
  }
  if (l1) {
    const h16* wr = Wih1 + (size_t)(w * 512 + g * 16 + nl) * 512 + qd * 8;
    #pragma unroll
    for (int kt = 0; kt < 16; ++kt) a_ih[kt] = *(const h16x8*)(wr + kt * 32);
  }
  const float* bias = l1 ? bias1 : bias0;
  float bias_v[4];
  #pragma unroll
  for (int r = 0; r < 4; ++r) bias_v[r] = bias[w * 512 + g * 16 + qd * 4 + r];

  c_st[tid >> 4][tid & 15] = 0.f;
  for (int i = tid; i < 16 * 520; i += 256) { Hst0[i] = (h16)0.f; Hst1[i] = (h16)0.f; }
  __syncthreads();

  unsigned* myring = l1 ? H1ring : H0ring;

  for (int t = 0; t < T_; ++t) {
    f32x4 acc = {0.f, 0.f, 0.f, 0.f};
    h16x4 gv = {};

    if (!l1) {
      // G load first: HBM latency hides under the poll
      gv = *(const h16x4*)(G + ((size_t)nl * T_ + t) * G4_ + w * 512 + g * 16 + qd * 4);
      // back-pressure: H1 tag >= t-3 in slot (t-3)&3; one u64/thread covers all 32 L1 WGs
      if (t >= 4) {
        const unsigned bt = (unsigned)(t - 3);
        const unsigned long long* bp = (const unsigned long long*)
            (H1ring + ((size_t)((t - 3) & 3) * 16 + sample) * 512
             + chunk * 32 + (sample & 1) * 16);
        for (;;) {
          unsigned long long v = __hip_atomic_load(bp, __ATOMIC_RELAXED, __HIP_MEMORY_SCOPE_AGENT);
          if (((unsigned)(v >> 16) & 0xffffu) >= bt && (unsigned)(v >> 48) >= bt) break;
          __builtin_amdgcn_s_sleep(1);
        }
      }
      if (t > 0) poll_ring(H0ring, t & 3, (unsigned)t, sample, chunk, Hst0);
      if (tid == 0) mword = maskbits[t];
      __syncthreads();                               // Hst0 + mword ready
      if (t > 0) {
        #pragma unroll
        for (int kt = 0; kt < 16; ++kt) {
          h16x8 bfr = *(const h16x8*)(Hst0 + nl * 520 + kt * 32 + qd * 8);
          acc = __builtin_amdgcn_mfma_f32_16x16x32_f16(a_hh[kt], bfr, acc, 0, 0, 0);
        }
      }
    } else {
      if (t > 0) poll_ring(H1ring, t & 3, (unsigned)t, sample, chunk, Hst1);
      if (tid == 0) mword = maskbits[t];
      __syncthreads();                               // Hst1 + mword ready
      if (t > 0) {
        #pragma unroll
        for (int kt = 0; kt < 16; ++kt) {
          h16x8 bfr = *(const h16x8*)(Hst1 + nl * 520 + kt * 32 + qd * 8);
          acc = __builtin_amdgcn_mfma_f32_16x16x32_f16(a_hh[kt], bfr, acc, 0, 0, 0);
        }
      }
      poll_ring(H0ring, (t + 1) & 3, (unsigned)(t + 1), sample, chunk, Hst0);
      __syncthreads();                               // Hst0 ready
      #pragma unroll
      for (int kt = 0; kt < 16; ++kt) {
        h16x8 bfr = *(const h16x8*)(Hst0 + nl * 520 + kt * 32 + qd * 8);
        acc = __builtin_amdgcn_mfma_f32_16x16x32_f16(a_ih[kt], bfr, acc, 0, 0, 0);
      }
    }

    // activations (wave-uniform gate type)
    #pragma unroll
    for (int r = 0; r < 4; ++r) {
      float pre = acc[r] + bias_v[r] + (l1 ? 0.f : (float)gv[r]);
      float a = (w == 2) ? tanh_f(pre) : sigm(pre);
      gate_ex[w][qd * 4 + r][nl] = a;
    }
    __syncthreads();
    {
      const int jj = tid >> 4, n = tid & 15;
      float iv = gate_ex[0][jj][n], fv = gate_ex[1][jj][n];
      float gg = gate_ex[2][jj][n], ov = gate_ex[3][jj][n];
      float c_old = c_st[jj][n];
      bool msk = (mword >> n) & 1u;
      float c_new = msk ? (fv * c_old + iv * gg) : c_old;
      const h16* Hprev = l1 ? Hst1 : Hst0;
      float h_old = (float)Hprev[n * 520 + g * 16 + jj];
      float h_new = msk ? (ov * tanh_f(c_new)) : h_old;
      c_st[jj][n] = c_new;
      h16 hh = (h16)h_new;
      unsigned short hb; __builtin_memcpy(&hb, &hh, 2);
      unsigned pv = ((unsigned)(t + 1) << 16) | (unsigned)hb;
      __hip_atomic_store(myring + ((size_t)(((t + 1) & 3) * 16) + n) * 512 + g * 16 + jj, pv,
                         __ATOMIC_RELAXED, __HIP_MEMORY_SCOPE_AGENT);
      if (l1 && t == T_ - 1) hT_out[n * H_ + g * 16 + jj] = h_new;
    }
    __syncthreads();   // protect LDS state + rings for next iteration
  }
}

// ---------------- final FC: out = hT @ Wfc^T + bfc (fp32) ----------------
__global__ void k_fc(const float* __restrict__ hT, const float* __restrict__ Wfc,
                     const float* __restrict__ bfc, float* __restrict__ out) {
  const int b = blockIdx.x;
  __shared__ float hs[H_];
  for (int i = threadIdx.x; i < H_; i += 256) hs[i] = hT[(size_t)b * H_ + i];
  __syncthreads();
  const int o = threadIdx.x;
  const float* wr = Wfc + (size_t)o * H_;
  float s = bfc[o];
  for (int k = 0; k < H_; k += 4) {
    f32x4 w4 = *(const f32x4*)(wr + k);
    s += hs[k] * w4.x + hs[k + 1] * w4.y + hs[k + 2] * w4.z + hs[k + 3] * w4.w;
  }
  out[(size_t)b * O_ + o] = s;
}

extern "C" void kernel_launch(void* const* d_in, const int* in_sizes, int n_in,
                              void* d_out, int out_size, void* d_ws, size_t ws_size,
                              hipStream_t stream) {
  const float* x    = (const float*)d_in[0];
  const float* Wih0 = (const float*)d_in[1];
  const float* Whh0 = (const float*)d_in[2];
  const float* bih0 = (const float*)d_in[3];
  const float* bhh0 = (const float*)d_in[4];
  const float* Wih1 = (const float*)d_in[5];
  const float* Whh1 = (const float*)d_in[6];
  const float* bih1 = (const float*)d_in[7];
  const float* bhh1 = (const float*)d_in[8];
  const float* Wfc  = (const float*)d_in[9];
  const float* bfc  = (const float*)d_in[10];

  char* base = (char*)d_ws;
  size_t off = 0;
  auto alloc = [&](size_t bytes) -> void* {
    void* r = base + off;
    off = (off + bytes + 255) & ~(size_t)255;
    return r;
  };
  h16* Xh   = (h16*)alloc((size_t)BT_ * D_ * 2);
  h16* Gbuf = (h16*)alloc((size_t)BT_ * G4_ * 2);
  h16* Wb0  = (h16*)alloc((size_t)G4_ * D_ * 2);
  h16* Wb1  = (h16*)alloc((size_t)G4_ * H_ * 2);   // Whh0
  h16* Wb2  = (h16*)alloc((size_t)G4_ * H_ * 2);   // Wih1
  h16* Wb3  = (h16*)alloc((size_t)G4_ * H_ * 2);   // Whh1
  float* bs0 = (float*)alloc(G4_ * 4);
  float* bs1 = (float*)alloc(G4_ * 4);
  unsigned* maskbits = (unsigned*)alloc(T_ * 4);
  unsigned* H0ring = (unsigned*)alloc((size_t)4 * 16 * 512 * 4);
  unsigned* H1ring = (unsigned*)alloc((size_t)4 * 16 * 512 * 4);
  float* hT = (float*)alloc((size_t)B_ * H_ * 4);

  hipMemsetAsync(maskbits, 0, T_ * 4, stream);
  hipMemsetAsync(H0ring, 0, (size_t)4 * 16 * 512 * 4, stream);
  hipMemsetAsync(H1ring, 0, (size_t)4 * 16 * 512 * 4, stream);
  k_prep_x<<<BT_, 256, 0, stream>>>(x, Xh, maskbits);
  const int wn4 = G4_ * D_ / 4;
  k_cvt<<<(wn4 + 255) / 256, 256, 0, stream>>>(Wih0, Wb0, wn4);
  k_cvt<<<(wn4 + 255) / 256, 256, 0, stream>>>(Whh0, Wb1, wn4);
  k_cvt<<<(wn4 + 255) / 256, 256, 0, stream>>>(Wih1, Wb2, wn4);
  k_cvt<<<(wn4 + 255) / 256, 256, 0, stream>>>(Whh1, Wb3, wn4);
  k_bias<<<(G4_ + 255) / 256, 256, 0, stream>>>(bih0, bhh0, bs0, G4_);
  k_bias<<<(G4_ + 255) / 256, 256, 0, stream>>>(bih1, bhh1, bs1, G4_);

  k_gemm<<<(BT_ / 128) * (G4_ / 128), 256, 0, stream>>>(Xh, Wb0, Gbuf, BT_, G4_, D_);
  k_lstm2<<<64, 256, 0, stream>>>(Gbuf, Wb1, Wb2, Wb3, bs0, bs1, maskbits,
                                  H0ring, H1ring, hT);
  k_fc<<<B_, 256, 0, stream>>>(hT, Wfc, bfc, (float*)d_out);
}